// Round 13
// baseline (1571.800 us; speedup 1.0000x reference)
//
#include <hip/hip_runtime.h>
#include <hip/hip_cooperative_groups.h>

namespace cg = cooperative_groups;

#define KBINS  10
#define SBIN   100
#define BETA   0.9f
#define THR    1.0f
#define CDIV(a,b) (((a)+(b)-1)/(b))

// Padded spike layouts (halo zeros): spk1p [1000][4][52][192],
// spk2p [1000][8][27][100], spk3p [1000][16][15][54]. Bases are raw+63 so the
// +1 halo offset keeps wave stores 64B-aligned.

struct MegaParams {
    const float *x, *w1, *b1, *w2, *b2, *w3, *b3, *w4, *b4;
    const float *dw4, *db4, *dw3, *db3, *dw2, *db2, *dw1, *db1, *wo, *bo;
    float* out;
    float* cbuf;
    unsigned char *spk1r;
    unsigned char *spk1p, *spk2p, *spk3p;
    float *skip0, *skip1, *skip2, *skip3, *msS;
    float *d4, *d3, *d2, *d1, *cat3, *cat2, *cat1, *part;
};

// ---------------- stage bodies (grid-stride, shared by both paths) ---------

__device__ inline void st_zero(unsigned char* base, int n16, int tid, int NT) {
    float4* z = (float4*)base;
    for (int i = tid; i < n16; i += NT)
        z[i] = make_float4(0.f, 0.f, 0.f, 0.f);
}

__device__ inline void st_conv1(const float* x, const float* w1, const float* b1,
                                float* cbuf, int q, int tid, int NT) {
    const int N = 500 * 50 * 46;
    const float* xb = x + (size_t)q * 500 * 36800;
    for (int n = tid; n < N; n += NT) {
        int wq  = n % 46;
        int tmp = n / 46;
        int h   = tmp % 50;
        int t   = tmp / 50;
        int w0  = wq * 4;

        const float* xt = xb + (size_t)t * 36800;
        float rm2 = (h  < 49)  ? 1.f : 0.f;
        float cm8 = (w0 < 180) ? 1.f : 0.f;
        int   r2  = min(2 * h + 2, 99);
        int   cb  = 2 * w0;
        int   c8  = min(cb + 8, 367);

        const float* row0 = xt + (2 * h) * 368 + cb;
        const float* row1 = row0 + 368;
        const float* row2 = xt + r2 * 368 + cb;

        float tap[3][9];
        #pragma unroll
        for (int j = 0; j < 8; j++) {
            tap[0][j] = row0[j];
            tap[1][j] = row1[j];
            tap[2][j] = row2[j] * rm2;
        }
        tap[0][8] = xt[(2 * h) * 368 + c8] * cm8;
        tap[1][8] = xt[(2 * h + 1) * 368 + c8] * cm8;
        tap[2][8] = xt[r2 * 368 + c8] * (rm2 * cm8);

        float* ot = cbuf + (size_t)t * 36800 + h * 184 + w0;
        #pragma unroll
        for (int co = 0; co < 4; co++) {
            float b = b1[co];
            float a0 = b, a1 = b, a2 = b, a3 = b;
            #pragma unroll
            for (int r = 0; r < 3; r++) {
                #pragma unroll
                for (int kw = 0; kw < 3; kw++) {
                    float wv = w1[co * 9 + r * 3 + kw];
                    a0 = fmaf(tap[r][0 + kw], wv, a0);
                    a1 = fmaf(tap[r][2 + kw], wv, a1);
                    a2 = fmaf(tap[r][4 + kw], wv, a2);
                    a3 = fmaf(tap[r][6 + kw], wv, a3);
                }
            }
            *(float4*)(ot + (size_t)co * 9200) = make_float4(a0, a1, a2, a3);
        }
    }
}

__device__ inline void st_scan(const float* cbuf, unsigned char* spk,
                               float* skip, float* mstate,
                               int C, int HW, int Win, int Wp, int HpWp,
                               int write_spk, int bin0, int nbins, int init,
                               int tid, int NT) {
    const int PF = 20;
    int CHW = C * HW;
    for (int p = tid; p < CHW; p += NT) {
        int c  = p / HW;
        int hw = p - c * HW;
        int h  = hw / Win, w = hw - h * Win;

        const size_t tstr = (size_t)C * HpWp;
        unsigned char* sp = spk + (size_t)bin0 * SBIN * tstr
                          + (size_t)c * HpWp + (h + 1) * Wp + (w + 1);

        float m = init ? 0.0f : mstate[p];
        float va[PF], vb[PF];
        #pragma unroll
        for (int j = 0; j < PF; j++) va[j] = cbuf[(size_t)j * CHW + p];

        const int T = nbins * SBIN;
        for (int k = 0; k < nbins; k++) {
            float s = 0.0f, q = 0.0f;
            for (int b = 0; b < SBIN / PF; b++) {
                int t0 = k * SBIN + b * PF;
                int tn = t0 + PF;
                bool more = (tn < T);
                #pragma unroll
                for (int j = 0; j < PF; j++)
                    vb[j] = more ? cbuf[(size_t)(tn + j) * CHW + p] : 0.0f;
                #pragma unroll
                for (int j = 0; j < PF; j++) {
                    m = fmaf(m, BETA, va[j]);
                    float spv = (m - THR > 0.0f) ? 1.0f : 0.0f;
                    m -= spv * THR;
                    if (write_spk) sp[(size_t)(t0 + j) * tstr] = (unsigned char)spv;
                    s += m;
                    q = fmaf(m, m, q);
                }
                #pragma unroll
                for (int j = 0; j < PF; j++) va[j] = vb[j];
            }
            int g = bin0 + k;
            float mean = s * (1.0f / SBIN);
            float var  = q * (1.0f / SBIN) - mean * mean;
            float sd   = sqrtf(fmaxf(var, 1e-8f));
            skip[(size_t)(g * 2 * C + c) * HW + hw]     = mean;
            skip[(size_t)(g * 2 * C + C + c) * HW + hw] = sd;
        }
        mstate[p] = m;
    }
}

template<int CIN, int COUT, int COG, int OW,
         int HOUT, int WOUT, int PADH, int HP, int WP, int NCOG>
__device__ inline void st_convs2(const unsigned char* spk, const float* wt,
                                 const float* bias, float* out,
                                 int tid, int NT) {
    const int WQ  = (WOUT + OW - 1) / OW;
    const int NB  = 1000 * HOUT * WQ;
    const int NBr = (NB + 63) & ~63;
    const int NT9 = 2 * OW + 1;
    for (int i = tid; i < NBr * NCOG; i += NT) {
        int cog = i / NBr;
        int n   = i - cog * NBr;
        bool ok = (n < NB);
        n = ok ? n : 0;
        int wq  = n % WQ;
        int tmp = n / WQ;
        int h   = tmp % HOUT;
        int t   = tmp / HOUT;
        int w0  = wq * OW;

        const unsigned char* base = spk + (size_t)t * CIN * HP * WP
                                  + (2 * h - PADH + 1) * WP + (2 * w0 + 1);

        float acc[OW][COG];
        #pragma unroll
        for (int q = 0; q < OW; q++)
            #pragma unroll
            for (int co = 0; co < COG; co++) acc[q][co] = bias[cog * COG + co];

        for (int ci = 0; ci < CIN; ci++) {
            const unsigned char* ic = base + (size_t)ci * HP * WP;
            float tap[3][NT9];
            #pragma unroll
            for (int r = 0; r < 3; r++)
                #pragma unroll
                for (int j = 0; j < NT9; j++)
                    tap[r][j] = (float)ic[r * WP + j];
            #pragma unroll
            for (int co = 0; co < COG; co++) {
                const float* wc = wt + ((size_t)(cog * COG + co) * CIN + ci) * 9;
                #pragma unroll
                for (int r = 0; r < 3; r++)
                    #pragma unroll
                    for (int kw = 0; kw < 3; kw++) {
                        float wv = wc[r * 3 + kw];
                        #pragma unroll
                        for (int q = 0; q < OW; q++)
                            acc[q][co] = fmaf(tap[r][2 * q + kw], wv, acc[q][co]);
                    }
            }
        }

        if (ok) {
            float* ot = out + ((size_t)t * COUT + cog * COG) * (HOUT * WOUT)
                      + h * WOUT + w0;
            #pragma unroll
            for (int co = 0; co < COG; co++) {
                float* oc = ot + (size_t)co * (HOUT * WOUT);
                if constexpr (OW == 4) {
                    *(float4*)oc = make_float4(acc[0][co], acc[1][co],
                                               acc[2][co], acc[3][co]);
                } else {
                    if (w0 + 2 <= WOUT) *(float2*)oc = make_float2(acc[0][co], acc[1][co]);
                    else                oc[0] = acc[0][co];
                }
            }
        }
    }
}

__device__ inline void st_upcat(const float* up_src, int Cup, int Hi, int Wi,
                                const float* skip, int Cskip,
                                float* out, int Ho, int Wo, int tid, int NT) {
    int total = (Cup + Cskip) * Ho * Wo;
    for (int n = tid; n < total; n += NT) {
        int w   = n % Wo;
        int tmp = n / Wo;
        int h   = tmp % Ho;
        int c   = tmp / Ho;
        float v;
        if (c < Cup) {
            float ph = (h + 0.5f) * (float)Hi / (float)Ho - 0.5f;
            float pw = (w + 0.5f) * (float)Wi / (float)Wo - 0.5f;
            float fh = floorf(ph), fw = floorf(pw);
            int h0 = (int)fh, w0 = (int)fw;
            float ah = ph - fh, aw = pw - fw;
            int h0c = min(max(h0, 0), Hi - 1), h1c = min(max(h0 + 1, 0), Hi - 1);
            int w0c = min(max(w0, 0), Wi - 1), w1c = min(max(w0 + 1, 0), Wi - 1);
            const float* sc = up_src + (size_t)c * Hi * Wi;
            float v00 = sc[h0c * Wi + w0c], v01 = sc[h0c * Wi + w1c];
            float v10 = sc[h1c * Wi + w0c], v11 = sc[h1c * Wi + w1c];
            v = (1.0f - ah) * ((1.0f - aw) * v00 + aw * v01)
              + ah * ((1.0f - aw) * v10 + aw * v11);
        } else {
            v = skip[(size_t)(c - Cup) * Ho * Wo + h * Wo + w];
        }
        out[n] = v;
    }
}

template<int CIN, int CS, int COG>
__device__ inline void st_dconv(const float* in, const float* wt, float* part,
                                int Cout, int H, int W, int nchunks,
                                int tid, int NT) {
    int HW  = H * W;
    int HWr = (HW + 63) & ~63;
    int ncog = Cout / COG;
    int total = nchunks * ncog * HWr;
    for (int i = tid; i < total; i += NT) {
        int pix = i % HWr;
        int r   = i / HWr;
        int co0   = (r % ncog) * COG;
        int chunk = r / ncog;
        bool ok = (pix < HW);
        pix = ok ? pix : 0;
        int h = pix / W, w = pix - h * W;

        int off[9]; float msk[9];
        #pragma unroll
        for (int kh = 0; kh < 3; kh++) {
            int rr = h + kh - 1;
            bool rok = (rr >= 0) && (rr < H);
            int rc = rok ? rr : 0;
            #pragma unroll
            for (int kw = 0; kw < 3; kw++) {
                int cc = w + kw - 1;
                bool cok = (cc >= 0) && (cc < W);
                int ccc = cok ? cc : 0;
                off[kh * 3 + kw] = rc * W + ccc;
                msk[kh * 3 + kw] = (rok && cok) ? 1.0f : 0.0f;
            }
        }

        const float* ibase = in + (size_t)chunk * CS * HW;
        const float* wbase = wt + ((size_t)co0 * CIN + (size_t)chunk * CS) * 9;

        float acc[COG];
        #pragma unroll
        for (int co = 0; co < COG; co++) acc[co] = 0.0f;

        #pragma unroll 8
        for (int ci = 0; ci < CS; ci++) {
            const float* ic = ibase + (size_t)ci * HW;
            float tap[9];
            #pragma unroll
            for (int j = 0; j < 9; j++)
                tap[j] = msk[j] * ic[off[j]];
            #pragma unroll
            for (int co = 0; co < COG; co++) {
                const float* wc = wbase + ((size_t)co * CIN + ci) * 9;
                #pragma unroll
                for (int j = 0; j < 9; j++)
                    acc[co] = fmaf(tap[j], wc[j], acc[co]);
            }
        }

        if (ok) {
            float* pp = part + ((size_t)chunk * Cout + co0) * HW + pix;
            #pragma unroll
            for (int co = 0; co < COG; co++) pp[(size_t)co * HW] = acc[co];
        }
    }
}

__device__ inline void st_reduce(const float* part, const float* bias,
                                 float* out, int Cout, int HW, int nchunks,
                                 int tid, int NT) {
    int total = Cout * HW;
    for (int n = tid; n < total; n += NT) {
        int co = n / HW;
        float acc = bias[co];
        for (int c = 0; c < nchunks; c++)
            acc += part[(size_t)c * Cout * HW + n];
        out[n] = fmaxf(acc, 0.0f);
    }
}

__device__ inline void st_final(const float* d1, const float* wo,
                                const float* bo, float* out, int tid, int NT) {
    for (int n = tid; n < 36800; n += NT) {
        int w = n % 368, h = n / 368;
        float ph = (h + 0.5f) * 0.5f - 0.5f;
        float pw = (w + 0.5f) * 0.5f - 0.5f;
        float fh = floorf(ph), fw = floorf(pw);
        int h0 = (int)fh, w0 = (int)fw;
        float ah = ph - fh, aw = pw - fw;
        int h0c = min(max(h0, 0), 49),  h1c = min(max(h0 + 1, 0), 49);
        int w0c = min(max(w0, 0), 183), w1c = min(max(w0 + 1, 0), 183);
        float acc = bo[0];
        #pragma unroll
        for (int c = 0; c < 8; c++) {
            const float* sc = d1 + c * 9200;
            float v00 = sc[h0c * 184 + w0c], v01 = sc[h0c * 184 + w1c];
            float v10 = sc[h1c * 184 + w0c], v11 = sc[h1c * 184 + w1c];
            float v = (1.0f - ah) * ((1.0f - aw) * v00 + aw * v01)
                    + ah * ((1.0f - aw) * v10 + aw * v11);
            acc = fmaf(wo[c], v, acc);
        }
        out[n] = acc;
    }
}

// --------------------------- cooperative mega kernel -----------------------
__global__ void __launch_bounds__(256, 2) k_mega(MegaParams P) {
    cg::grid_group grid = cg::this_grid();
    const int tid = blockIdx.x * 256 + threadIdx.x;
    const int NT  = gridDim.x * 256;

    st_zero(P.spk1r, 74496768 / 16, tid, NT);
    grid.sync();

    for (int q = 0; q < 2; q++) {
        st_conv1(P.x, P.w1, P.b1, P.cbuf, q, tid, NT);
        grid.sync();
        st_scan(P.cbuf, P.spk1p, P.skip0, P.msS, 4, 9200, 184, 192, 9984,
                1, 5 * q, 5, (q == 0) ? 1 : 0, tid, NT);
        grid.sync();
    }

    st_convs2<4, 8, 8, 4, 25, 92, 0, 52, 192, 1>(P.spk1p, P.w2, P.b2, P.cbuf, tid, NT);
    grid.sync();
    st_scan(P.cbuf, P.spk2p, P.skip1, P.msS, 8, 2300, 92, 100, 2700,
            1, 0, 10, 1, tid, NT);
    grid.sync();

    st_convs2<8, 16, 16, 2, 13, 46, 1, 27, 100, 1>(P.spk2p, P.w3, P.b3, P.cbuf, tid, NT);
    grid.sync();
    st_scan(P.cbuf, P.spk3p, P.skip2, P.msS, 16, 598, 46, 54, 810,
            1, 0, 10, 1, tid, NT);
    grid.sync();

    st_convs2<16, 32, 16, 2, 7, 23, 1, 15, 54, 2>(P.spk3p, P.w4, P.b4, P.cbuf, tid, NT);
    grid.sync();
    st_scan(P.cbuf, P.spk1p /*unused*/, P.skip3, P.msS, 32, 161, 23, 31, 279,
            0, 0, 10, 1, tid, NT);
    grid.sync();

    st_dconv<640, 32, 4>(P.skip3, P.dw4, P.part, 64, 7, 23, 20, tid, NT);
    grid.sync();
    st_reduce(P.part, P.db4, P.d4, 64, 161, 20, tid, NT);
    grid.sync();
    st_upcat(P.d4, 64, 7, 23, P.skip2, 320, P.cat3, 13, 46, tid, NT);
    grid.sync();
    st_dconv<384, 32, 4>(P.cat3, P.dw3, P.part, 32, 13, 46, 12, tid, NT);
    grid.sync();
    st_reduce(P.part, P.db3, P.d3, 32, 598, 12, tid, NT);
    grid.sync();
    st_upcat(P.d3, 32, 13, 46, P.skip1, 160, P.cat2, 25, 92, tid, NT);
    grid.sync();
    st_dconv<192, 32, 4>(P.cat2, P.dw2, P.part, 16, 25, 92, 6, tid, NT);
    grid.sync();
    st_reduce(P.part, P.db2, P.d2, 16, 2300, 6, tid, NT);
    grid.sync();
    st_upcat(P.d2, 16, 25, 92, P.skip0, 80, P.cat1, 50, 184, tid, NT);
    grid.sync();
    st_dconv<96, 32, 4>(P.cat1, P.dw1, P.part, 8, 50, 184, 3, tid, NT);
    grid.sync();
    st_reduce(P.part, P.db1, P.d1, 8, 9200, 3, tid, NT);
    grid.sync();

    st_final(P.d1, P.wo, P.bo, P.out, tid, NT);
}

// --------------------------- fallback wrappers -----------------------------
#define TIDNT int tid = blockIdx.x * blockDim.x + threadIdx.x; \
              int NT = gridDim.x * blockDim.x;

__global__ void g_zero(unsigned char* base, int n16) { TIDNT; st_zero(base, n16, tid, NT); }
__global__ void g_conv1(const float* x, const float* w1, const float* b1,
                        float* cbuf, int q) { TIDNT; st_conv1(x, w1, b1, cbuf, q, tid, NT); }
__global__ void g_scan(const float* cbuf, unsigned char* spk, float* skip,
                       float* mstate, int C, int HW, int Win, int Wp, int HpWp,
                       int write_spk, int bin0, int nbins, int init) {
    TIDNT; st_scan(cbuf, spk, skip, mstate, C, HW, Win, Wp, HpWp,
                   write_spk, bin0, nbins, init, tid, NT);
}
template<int CIN, int COUT, int COG, int OW,
         int HOUT, int WOUT, int PADH, int HP, int WP, int NCOG>
__global__ void g_convs2(const unsigned char* spk, const float* wt,
                         const float* bias, float* out) {
    TIDNT; st_convs2<CIN, COUT, COG, OW, HOUT, WOUT, PADH, HP, WP, NCOG>(
        spk, wt, bias, out, tid, NT);
}
__global__ void g_upcat(const float* u, int Cup, int Hi, int Wi,
                        const float* s, int Cs, float* o, int Ho, int Wo) {
    TIDNT; st_upcat(u, Cup, Hi, Wi, s, Cs, o, Ho, Wo, tid, NT);
}
template<int CIN, int CS, int COG>
__global__ void g_dconv(const float* in, const float* wt, float* part,
                        int Cout, int H, int W, int nchunks) {
    TIDNT; st_dconv<CIN, CS, COG>(in, wt, part, Cout, H, W, nchunks, tid, NT);
}
__global__ void g_reduce(const float* part, const float* bias, float* out,
                         int Cout, int HW, int nchunks) {
    TIDNT; st_reduce(part, bias, out, Cout, HW, nchunks, tid, NT);
}
__global__ void g_final(const float* d1, const float* wo, const float* bo,
                        float* out) { TIDNT; st_final(d1, wo, bo, out, tid, NT); }

// ---------------------------------------------------------------------------
extern "C" void kernel_launch(void* const* d_in, const int* in_sizes, int n_in,
                              void* d_out, int out_size, void* d_ws, size_t ws_size,
                              hipStream_t stream) {
    (void)in_sizes; (void)n_in; (void)out_size; (void)ws_size;

    MegaParams P;
    P.x   = (const float*)d_in[0];
    P.w1  = (const float*)d_in[1];  P.b1 = (const float*)d_in[2];
    P.w2  = (const float*)d_in[3];  P.b2 = (const float*)d_in[4];
    P.w3  = (const float*)d_in[5];  P.b3 = (const float*)d_in[6];
    P.w4  = (const float*)d_in[7];  P.b4 = (const float*)d_in[8];
    P.dw4 = (const float*)d_in[9];  P.db4 = (const float*)d_in[10];
    P.dw3 = (const float*)d_in[11]; P.db3 = (const float*)d_in[12];
    P.dw2 = (const float*)d_in[13]; P.db2 = (const float*)d_in[14];
    P.dw1 = (const float*)d_in[15]; P.db1 = (const float*)d_in[16];
    P.wo  = (const float*)d_in[17]; P.bo  = (const float*)d_in[18];
    P.out = (float*)d_out;

    char* ws = (char*)d_ws;
    size_t off = 0;
    auto alloc = [&](size_t bytes) -> void* {
        void* p = ws + off;
        off += (bytes + 255) & ~(size_t)255;
        return p;
    };
    P.cbuf  = (float*)alloc(73600000);
    P.spk1r = (unsigned char*)alloc(39936000 + 256);
    unsigned char* spk2r = (unsigned char*)alloc(21600000 + 256);
    unsigned char* spk3r = (unsigned char*)alloc(12960000 + 256);
    P.spk1p = P.spk1r + 63;
    P.spk2p = spk2r + 63;
    P.spk3p = spk3r + 63;
    P.skip0 = (float*)alloc(2944000);
    P.skip1 = (float*)alloc(1472000);
    P.skip2 = (float*)alloc(765440);
    P.skip3 = (float*)alloc(412160);
    P.msS   = (float*)alloc(147200);
    char* dec = (char*)P.cbuf;
    size_t doff = 0;
    auto dalloc = [&](size_t bytes) -> void* {
        void* p = dec + doff;
        doff += (bytes + 255) & ~(size_t)255;
        return p;
    };
    P.d4   = (float*)dalloc(10304u * 4);
    P.d3   = (float*)dalloc(19136u * 4);
    P.d2   = (float*)dalloc(36800u * 4);
    P.d1   = (float*)dalloc(73600u * 4);
    P.cat3 = (float*)dalloc(229632u * 4);
    P.cat2 = (float*)dalloc(441600u * 4);
    P.cat1 = (float*)dalloc(883200u * 4);
    P.part = (float*)dalloc(230400u * 4);

    // ---- try cooperative single-dispatch path ----
    bool coop_ok = false;
    {
        int occ = 0;
        hipError_t e = hipOccupancyMaxActiveBlocksPerMultiprocessor(
            &occ, (const void*)k_mega, 256, 0);
        if (e == hipSuccess && occ >= 1) {
            int grid = (occ >= 2) ? 512 : 256;   // 256 CUs x min(occ,2)
            void* args[] = { &P };
            e = hipLaunchCooperativeKernel((const void*)k_mega, dim3(grid),
                                           dim3(256), args, 0, stream);
            coop_ok = (e == hipSuccess);
        }
    }
    if (coop_ok) return;

    // ---- fallback: proven multi-dispatch sequence (same stage bodies) ----
    const int BS = 256, SBS = 64;
    g_zero<<<CDIV(74496768 / 16, BS), BS, 0, stream>>>(P.spk1r, 74496768 / 16);

    for (int q = 0; q < 2; q++) {
        g_conv1<<<CDIV(500 * 50 * 46, BS), BS, 0, stream>>>(P.x, P.w1, P.b1, P.cbuf, q);
        g_scan<<<CDIV(36800, SBS), SBS, 0, stream>>>(
            P.cbuf, P.spk1p, P.skip0, P.msS, 4, 9200, 184, 192, 9984,
            1, 5 * q, 5, (q == 0) ? 1 : 0);
    }

    g_convs2<4, 8, 8, 4, 25, 92, 0, 52, 192, 1>
        <<<CDIV(575040, BS), BS, 0, stream>>>(P.spk1p, P.w2, P.b2, P.cbuf);
    g_scan<<<CDIV(18400, SBS), SBS, 0, stream>>>(P.cbuf, P.spk2p, P.skip1, P.msS,
                                                 8, 2300, 92, 100, 2700, 1, 0, 10, 1);

    g_convs2<8, 16, 16, 2, 13, 46, 1, 27, 100, 1>
        <<<CDIV(299008, BS), BS, 0, stream>>>(P.spk2p, P.w3, P.b3, P.cbuf);
    g_scan<<<CDIV(9568, SBS), SBS, 0, stream>>>(P.cbuf, P.spk3p, P.skip2, P.msS,
                                                16, 598, 46, 54, 810, 1, 0, 10, 1);

    g_convs2<16, 32, 16, 2, 7, 23, 1, 15, 54, 2>
        <<<CDIV(168064, BS), BS, 0, stream>>>(P.spk3p, P.w4, P.b4, P.cbuf);
    g_scan<<<CDIV(5152, SBS), SBS, 0, stream>>>(P.cbuf, P.spk1p /*unused*/, P.skip3,
                                                P.msS, 32, 161, 23, 31, 279, 0, 0, 10, 1);

    g_dconv<640, 32, 4><<<CDIV(20 * 16 * 192, BS), BS, 0, stream>>>(
        P.skip3, P.dw4, P.part, 64, 7, 23, 20);
    g_reduce<<<CDIV(64 * 161, BS), BS, 0, stream>>>(P.part, P.db4, P.d4, 64, 161, 20);
    g_upcat<<<CDIV(384 * 598, BS), BS, 0, stream>>>(P.d4, 64, 7, 23,
                                                    P.skip2, 320, P.cat3, 13, 46);
    g_dconv<384, 32, 4><<<CDIV(12 * 8 * 640, BS), BS, 0, stream>>>(
        P.cat3, P.dw3, P.part, 32, 13, 46, 12);
    g_reduce<<<CDIV(32 * 598, BS), BS, 0, stream>>>(P.part, P.db3, P.d3, 32, 598, 12);
    g_upcat<<<CDIV(192 * 2300, BS), BS, 0, stream>>>(P.d3, 32, 13, 46,
                                                     P.skip1, 160, P.cat2, 25, 92);
    g_dconv<192, 32, 4><<<CDIV(6 * 4 * 2304, BS), BS, 0, stream>>>(
        P.cat2, P.dw2, P.part, 16, 25, 92, 6);
    g_reduce<<<CDIV(16 * 2300, BS), BS, 0, stream>>>(P.part, P.db2, P.d2, 16, 2300, 6);
    g_upcat<<<CDIV(96 * 9200, BS), BS, 0, stream>>>(P.d2, 16, 25, 92,
                                                    P.skip0, 80, P.cat1, 50, 184);
    g_dconv<96, 32, 4><<<CDIV(3 * 2 * 9216, BS), BS, 0, stream>>>(
        P.cat1, P.dw1, P.part, 8, 50, 184, 3);
    g_reduce<<<CDIV(8 * 9200, BS), BS, 0, stream>>>(P.part, P.db1, P.d1, 8, 9200, 3);
    g_final<<<CDIV(36800, BS), BS, 0, stream>>>(P.d1, P.wo, P.bo, P.out);
}